// Round 6
// baseline (986.365 us; speedup 1.0000x reference)
//
#include <hip/hip_runtime.h>

#define B_DIM 256
#define H_DIM 4608
#define K_X   512
#define K_TOT 5120

typedef __attribute__((ext_vector_type(8))) short    short8;   // 8 x bf16
typedef __attribute__((ext_vector_type(4))) float    floatx4;  // MFMA C/D frag
typedef __attribute__((ext_vector_type(4))) unsigned uintx4;

static __device__ __forceinline__ unsigned pkbf(float a, float b){
  unsigned ua = (__float_as_uint(a) + 0x8000u) >> 16;
  unsigned ub = (__float_as_uint(b) + 0x8000u) & 0xFFFF0000u;
  return ua | ub;
}
static __device__ __forceinline__ float sigm(float v){ return 1.0f / (1.0f + __expf(-v)); }
static __device__ __forceinline__ float tanh_fast(float v){
  float ax = fabsf(v);
  float e  = __expf(-2.0f * ax);
  float t  = (1.0f - e) / (1.0f + e);
  return copysignf(t, v);
}

// ---------- kernel 0: pack [x|h0] -> bf16 A (256x5120); zero z ----------
__global__ __launch_bounds__(256) void conv_kernel(
    const float* __restrict__ x, const float* __restrict__ h0,
    unsigned short* __restrict__ Abf, float* __restrict__ z)
{
  const int t = threadIdx.x;
  if (blockIdx.x == 0) ((float4*)z)[t] = make_float4(0.f, 0.f, 0.f, 0.f); // 1024 floats

  const long e = ((long)blockIdx.x * 256 + t) * 8;     // element index, 8 per thread
  const int  b = (int)(e / K_TOT);
  const int  k = (int)(e - (long)b * K_TOT);
  const float* src = (k < K_X) ? (x + (long)b * K_X + k)
                               : (h0 + (long)b * H_DIM + (k - K_X));
  float4 v0 = *(const float4*)src;
  float4 v1 = *(const float4*)(src + 4);
  uint4 wv;
  wv.x = pkbf(v0.x, v0.y); wv.y = pkbf(v0.z, v0.w);
  wv.z = pkbf(v1.x, v1.y); wv.w = pkbf(v1.z, v1.w);
  *(uint4*)(Abf + e) = wv;
}

// ---------- kernel 1: gatesT = [Wih|Whh] . [x|h0]^T  ([18432 x 256] fp32) ----
// Grid: 1152 blocks x 16 W-rows, full K=5120. 4 waves x 64 batch-cols each.
// No LDS, no barriers: W tile (2 KB/step) is L2-shared by the 4 waves; A-frags
// come straight from L2/L3-resident Abf. Each block writes a private,
// contiguous 16 KB slab of gatesT -- no partials, no cross-block lines.
__global__ __launch_bounds__(256, 4) void gatesT_kernel(
    const unsigned short* __restrict__ Abf,
    const float* __restrict__ Wih, const float* __restrict__ Whh,
    float* __restrict__ GT)
{
  const int t   = threadIdx.x;
  const int w   = t >> 6;
  const int l   = t & 63;
  const int q   = l >> 4;
  const int col = l & 15;
  const int m0  = blockIdx.x * 16;   // W-row group
  const int wb  = w * 64;            // batch-col base for this wave

  const float* __restrict__ pWx = Wih + (long)(m0 + col) * K_X   + q * 8;
  const float* __restrict__ pWh = Whh + (long)(m0 + col) * H_DIM + q * 8;
  const unsigned short* __restrict__ pA0 = Abf + (long)(wb + col) * K_TOT + q * 8;
  const unsigned short* __restrict__ pA1 = pA0 + (long)16 * K_TOT;
  const unsigned short* __restrict__ pA2 = pA0 + (long)32 * K_TOT;
  const unsigned short* __restrict__ pA3 = pA0 + (long)48 * K_TOT;

  floatx4 acc0 = {0.f,0.f,0.f,0.f}, acc1 = acc0, acc2 = acc0, acc3 = acc0;

#define GSTEP(PW, AOFF) do {                                                   \
    floatx4 w0 = *(const floatx4*)(PW);                                        \
    floatx4 w1 = *(const floatx4*)((PW) + 4);                                  \
    union { uintx4 u; short8 s; } cv;                                          \
    cv.u = (uintx4){ pkbf(w0.x,w0.y), pkbf(w0.z,w0.w),                         \
                     pkbf(w1.x,w1.y), pkbf(w1.z,w1.w) };                       \
    short8 af = cv.s;                                                          \
    acc0 = __builtin_amdgcn_mfma_f32_16x16x32_bf16(af, *(const short8*)(pA0 + (AOFF)), acc0, 0, 0, 0); \
    acc1 = __builtin_amdgcn_mfma_f32_16x16x32_bf16(af, *(const short8*)(pA1 + (AOFF)), acc1, 0, 0, 0); \
    acc2 = __builtin_amdgcn_mfma_f32_16x16x32_bf16(af, *(const short8*)(pA2 + (AOFF)), acc2, 0, 0, 0); \
    acc3 = __builtin_amdgcn_mfma_f32_16x16x32_bf16(af, *(const short8*)(pA3 + (AOFF)), acc3, 0, 0, 0); \
  } while (0)

  #pragma unroll 4
  for (int kt = 0; kt < 16; ++kt)          // x-part: k in [0,512)
    GSTEP(pWx + kt * 32, kt * 32);
  #pragma unroll 4
  for (int kt = 0; kt < 144; ++kt)         // h-part: k in [512,5120)
    GSTEP(pWh + kt * 32, K_X + kt * 32);
#undef GSTEP

  // D[m=q*4+r][n=wb+nt*16+col]: 4 x 64 B segments per store inst, all lines
  // fully covered within this block (private 16 rows x 1 KB).
  float* __restrict__ gp = GT + (long)(m0 + q * 4) * B_DIM + wb + col;
  #pragma unroll
  for (int r = 0; r < 4; ++r){
    gp[(long)r * B_DIM +  0] = acc0[r];
    gp[(long)r * B_DIM + 16] = acc1[r];
    gp[(long)r * B_DIM + 32] = acc2[r];
    gp[(long)r * B_DIM + 48] = acc3[r];
  }
}

// ---------- kernel 2: corner-turn + bias + LSTM cell + z[b,r] ----------
// Grid: 72 j-tiles x 2 batch-halves. Reads gatesT rows (coalesced), stages
// c0/x tiles via LDS transpose, writes outH/outC back [B][H] (coalesced).
__global__ __launch_bounds__(256) void cell_kernel(
    const float* __restrict__ GT, const float* __restrict__ c0,
    const float* __restrict__ bih, const float* __restrict__ bhh,
    const float* __restrict__ x,
    float* __restrict__ outH, float* __restrict__ outC, float* __restrict__ z)
{
  __shared__ float cs[128][67];
  __shared__ float hs[128][67];
  __shared__ float xs[128][67];

  const int t  = threadIdx.x;
  const int j0 = (blockIdx.x >> 1) * 64;
  const int bh = blockIdx.x & 1;
  const bool isDw2 = (j0 >= 2048) && (j0 < 4096);
  const int rIdx = (j0 - 2048) >> 9;
  const int i0   = (j0 - 2048) & 511;

  // stage c0 (and x if dw2 region) tiles: global rows coalesced (256 B)
  {
    const int jj = t & 63;
    const int bb = t >> 6;
    for (int p = 0; p < 32; ++p){
      const int b = p * 4 + bb;
      cs[b][jj] = c0[(long)(bh * 128 + b) * H_DIM + j0 + jj];
      if (isDw2) xs[b][jj] = x[(long)(bh * 128 + b) * K_X + i0 + jj];
    }
  }
  __syncthreads();

  // compute: thread (b = t&127, jh = t>>7) handles 32 j's; gatesT reads are
  // lane-contiguous in b (512 B per gate row).
  {
    const int b  = t & 127;
    const int jh = t >> 7;
    float zacc = 0.f;
    for (int jj = 0; jj < 32; ++jj){
      const int j  = jh * 32 + jj;
      const int jg = j0 + j;
      const long cbase = (long)jg * B_DIM + bh * 128 + b;
      float gi = GT[cbase]                            + bih[jg]             + bhh[jg];
      float gf = GT[cbase + (long)H_DIM * B_DIM]      + bih[H_DIM + jg]     + bhh[H_DIM + jg];
      float gg = GT[cbase + (long)2 * H_DIM * B_DIM]  + bih[2 * H_DIM + jg] + bhh[2 * H_DIM + jg];
      float go = GT[cbase + (long)3 * H_DIM * B_DIM]  + bih[3 * H_DIM + jg] + bhh[3 * H_DIM + jg];
      float cp = cs[b][j];
      float cn = sigm(gf) * cp + sigm(gi) * tanh_fast(gg);
      float hn = sigm(go) * tanh_fast(cn);
      cs[b][j] = cn;
      hs[b][j] = hn;
      if (isDw2) zacc += hn * xs[b][j];
    }
    if (isDw2) atomicAdd(&z[(bh * 128 + b) * 4 + rIdx], zacc);
  }
  __syncthreads();

  // flush outC/outH coalesced (256 B rows)
  {
    const int jj = t & 63;
    const int bb = t >> 6;
    for (int p = 0; p < 32; ++p){
      const int b = p * 4 + bb;
      outC[(long)(bh * 128 + b) * H_DIM + j0 + jj] = cs[b][jj];
      outH[(long)(bh * 128 + b) * H_DIM + j0 + jj] = hs[b][jj];
    }
  }
}

// ---------- kernel 3: y = x @ W0^T + dw1.z + db + b0  (MFMA, N-tile 16) ------
__global__ __launch_bounds__(256) void y_kernel(
    const unsigned short* __restrict__ Abf,
    const float* __restrict__ hnew,
    const float* __restrict__ W0, const float* __restrict__ b0,
    const float* __restrict__ z,
    float* __restrict__ y)
{
  __shared__ __align__(16) unsigned short Ws[16 * 512];  // 16 KB bf16 W0 tile, swizzled
  const int t    = threadIdx.x;
  const int w    = t >> 6;
  const int l    = t & 63;
  const int q    = l >> 4;
  const int col  = l & 15;
  const int n0   = blockIdx.x * 16;
  const int wrow = w * 64;

  {
    const int r  = t >> 4;
    const int kc = (t & 15) * 32;
    const float* src = W0 + (long)(n0 + r) * 512 + kc;
    #pragma unroll
    for (int j = 0; j < 4; ++j){
      float4 a = *(const float4*)(src + j * 8);
      float4 b = *(const float4*)(src + j * 8 + 4);
      uint4 wv;
      wv.x = pkbf(a.x, a.y); wv.y = pkbf(a.z, a.w);
      wv.z = pkbf(b.x, b.y); wv.w = pkbf(b.z, b.w);
      const int cch = (kc >> 3) + j;
      const int sw  = cch ^ (r & 7);
      *(uint4*)((char*)Ws + r * 1024 + sw * 16) = wv;
    }
  }
  __syncthreads();

  const long aBase = (long)(wrow + col) * K_TOT + q * 8;   // x lives in Abf cols 0..511
  floatx4 acc[4];
  #pragma unroll
  for (int mt = 0; mt < 4; ++mt) acc[mt] = (floatx4){0.f, 0.f, 0.f, 0.f};

  #pragma unroll 4
  for (int ks = 0; ks < 16; ++ks){
    const int sw = (ks * 4 + q) ^ (col & 7);
    short8 bf = *(const short8*)((char*)Ws + col * 1024 + sw * 16);
    #pragma unroll
    for (int mt = 0; mt < 4; ++mt){
      short8 af = *(const short8*)(Abf + aBase + ks * 32 + (long)mt * (16 * K_TOT));
      acc[mt] = __builtin_amdgcn_mfma_f32_16x16x32_bf16(af, bf, acc[mt], 0, 0, 0);
    }
  }

  const int   o  = n0 + col;
  const float bo = b0[o];
  #pragma unroll
  for (int mt = 0; mt < 4; ++mt){
    #pragma unroll
    for (int r2 = 0; r2 < 4; ++r2){
      const int brow = wrow + mt * 16 + q * 4 + r2;
      const float* hr = hnew + (long)brow * H_DIM;
      float4 d1 = *(const float4*)(hr + o * 4);        // dw1[b,o,0..3]
      float4 zr = *(const float4*)(z + brow * 4);      // z[b,0..3]
      float val = acc[mt][r2] + bo + hr[4096 + o]
                + d1.x * zr.x + d1.y * zr.y + d1.z * zr.z + d1.w * zr.w;
      y[(long)brow * 512 + o] = val;
    }
  }
}

extern "C" void kernel_launch(void* const* d_in, const int* in_sizes, int n_in,
                              void* d_out, int out_size, void* d_ws, size_t ws_size,
                              hipStream_t stream)
{
  (void)in_sizes; (void)n_in; (void)out_size; (void)ws_size;
  const float* x   = (const float*)d_in[0];
  const float* h0  = (const float*)d_in[1];
  const float* c0  = (const float*)d_in[2];
  const float* Wih = (const float*)d_in[3];
  const float* Whh = (const float*)d_in[4];
  const float* bih = (const float*)d_in[5];
  const float* bhh = (const float*)d_in[6];
  const float* W0  = (const float*)d_in[7];
  const float* b0  = (const float*)d_in[8];

  float* out  = (float*)d_out;
  float* y    = out;                       // 256*512
  float* outH = out + 131072;              // 256*4608
  float* outC = out + 131072 + 1179648;    // 256*4608

  unsigned short* Abf = (unsigned short*)d_ws;                          // 2.62 MB bf16 [x|h0]
  float* z  = (float*)((char*)d_ws + (size_t)B_DIM * K_TOT * 2);        // 4 KB (256 x 4)
  float* GT = (float*)((char*)d_ws + (size_t)B_DIM * K_TOT * 2 + 4096); // 18.9 MB gatesT [4H][B]

  hipLaunchKernelGGL(conv_kernel, dim3(640), dim3(256), 0, stream, x, h0, Abf, z);
  hipLaunchKernelGGL(gatesT_kernel, dim3(1152), dim3(256), 0, stream,
                     Abf, Wih, Whh, GT);
  hipLaunchKernelGGL(cell_kernel, dim3(144), dim3(256), 0, stream,
                     GT, c0, bih, bhh, x, outH, outC, z);
  hipLaunchKernelGGL(y_kernel, dim3(32), dim3(256), 0, stream, Abf, outH, W0, b0, z, y);
}